// Round 7
// baseline (80.677 us; speedup 1.0000x reference)
//
#include <hip/hip_runtime.h>
#include <hip/hip_bf16.h>

// Problem: B=2, N=1024, D=30, H=64, O=30  (all fp32)
//   zi = z @ W_r[:D], zj = z @ W_r[D:]
//   r_sum[b,i,h] = sum_j relu(zi[b,i,h] + zj[b,j,h] + b_r[h])
//   out[b,i,o]   = relu(sum_h r_sum[b,i,h]*W_a[h,o] + b_a[o])
//
// R6 post-mortem: abs-identity was neutral-to-worse (80.3 vs R4's 79.6) —
// inner loop is not marginally issue-bound; extra staging/reduction ate it.
// R7: revert to R4's proven inner loop; fold the zi projection into
// pairsum (each block computes its own 8 i-rows, ~0.2 us) so proj only
// computes zjb (half the FMAs, half the ws writes).
// Budget model: harness fixed cost ~74.6 us (40.3 fill + ~34 restore/gap),
// kernel portion ~5 us. This is the last structural work reduction.

#define BB 2
#define NN 1024
#define DD 30
#define HH 64
#define OO 30
#define JT 128      // j-tile rows staged in LDS per half (32 KB)
#define ITILE 8     // i rows per block

typedef float v2f __attribute__((ext_vector_type(2)));

// Kernel A: zjb[b,n,h] = (z @ W_r[D:])[b,n,h] + b_r[h]
__global__ __launch_bounds__(256) void proj_kernel(
    const float* __restrict__ z,    // [B*N, D]
    const float* __restrict__ Wr,   // [2D, H]
    const float* __restrict__ br,   // [H]
    float* __restrict__ zjb_out)    // [B*N, H]
{
    const int h = threadIdx.x;                      // 0..63
    const int r = blockIdx.x * 4 + threadIdx.y;     // row in [0, B*N)
    const float* zrow = z + (size_t)r * DD;
    float wj = 0.f;
#pragma unroll
    for (int d = 0; d < DD; ++d)
        wj += zrow[d] * Wr[(DD + d) * HH + h];      // zrow[d] wave-uniform
    zjb_out[(size_t)r * HH + h] = wj + br[h];
}

// Kernel B: in-block zi projection + pairwise relu-sum + fused epilogue.
// Grid: (N/ITILE, B). Block: (64, 8) = 512 threads, 8 waves (2/SIMD).
// Waves 0-3 (half 0): j in [0,512); waves 4-7 (half 1): j in [512,1024).
__global__ __launch_bounds__(512) void pairsum_kernel(
    const float* __restrict__ z,     // [B*N, D]
    const float* __restrict__ Wr,    // [2D, H] (first D rows used here)
    const float* __restrict__ zjb,   // [B*N, H]
    const float* __restrict__ Wa,    // [H, O]
    const float* __restrict__ ba,    // [O]
    float* __restrict__ out)         // [B*N, O]
{
    __shared__ float sj[2][JT * HH];        // 2 x 32 KB j-tiles
    __shared__ float racc[2][ITILE][HH];    // 2 x 2 KB partial r_sum rows
    __shared__ float zis[ITILE][HH];        // 2 KB zi rows for this block

    const int h  = threadIdx.x;          // 0..63
    const int w  = threadIdx.y;          // 0..7
    const int hf = w >> 2;               // j-half: 0 or 1
    const int wq = w & 3;                // wave-quad index within half
    const int t4 = wq * 64 + h;          // 0..255 within half
    const int b  = blockIdx.y;
    const int i0 = blockIdx.x * ITILE;

    // ---- in-block zi projection: wave w computes row i=w (64 h values) ----
    {
        const float* zrow = z + ((size_t)b * NN + i0 + w) * DD;
        float wi = 0.f;
#pragma unroll
        for (int d = 0; d < DD; ++d)
            wi += zrow[d] * Wr[d * HH + h];          // zrow[d] wave-uniform
        zis[w][h] = wi;
    }
    __syncthreads();

    v2f zv;
    zv.x = zis[wq * 2 + 0][h];
    zv.y = zis[wq * 2 + 1][h];
    v2f acc = {0.f, 0.f};

    // this half's 512-row slab of zjb
    const float* slab = zjb + ((size_t)b * NN + hf * (NN / 2)) * HH;

    for (int tile = 0; tile < (NN / 2) / JT; ++tile) {
        // cooperative stage: JT*HH = 8192 floats = 2048 float4, 8/thread
        const float4* src = (const float4*)(slab + (size_t)tile * JT * HH);
        float4* dst = (float4*)sj[hf];
#pragma unroll
        for (int k = 0; k < 8; ++k) dst[t4 + k * 256] = src[t4 + k * 256];
        __syncthreads();
        const float* sjt = sj[hf];
#pragma unroll 8
        for (int j = 0; j < JT; ++j) {
            const float zjv = sjt[j * HH + h];   // 2-way bank alias: free
            v2f tt = zv + zjv;                   // packable: v_pk_add_f32
            tt.x = fmaxf(tt.x, 0.f);             // v_max_f32 on pair regs
            tt.y = fmaxf(tt.y, 0.f);
            acc += tt;                           // packable: v_pk_add_f32
        }
        __syncthreads();
    }

    racc[hf][wq * 2 + 0][h] = acc.x;
    racc[hf][wq * 2 + 1][h] = acc.y;
    __syncthreads();

    // Epilogue: 8 rows x 30 outputs = 240 dots of length 64 (threads t<256)
    const int t = w * 64 + h;
    const int i = t >> 5;        // 0..7 for t<256
    const int o = t & 31;        // 0..31
    if (t < 256 && o < OO) {
        float s = ba[o];
#pragma unroll
        for (int hh = 0; hh < HH; ++hh)
            s += (racc[0][i][hh] + racc[1][i][hh]) * Wa[hh * OO + o];
        out[((size_t)b * NN + i0 + i) * OO + o] = fmaxf(s, 0.f);
    }
}

extern "C" void kernel_launch(void* const* d_in, const int* in_sizes, int n_in,
                              void* d_out, int out_size, void* d_ws, size_t ws_size,
                              hipStream_t stream) {
    const float* z_t = (const float*)d_in[0];   // [B,N,D]
    const float* W_r = (const float*)d_in[1];   // [2D,H]
    const float* b_r = (const float*)d_in[2];   // [H]
    const float* W_a = (const float*)d_in[3];   // [H,O]
    const float* b_a = (const float*)d_in[4];   // [O]
    float* out = (float*)d_out;                 // [B,N,O]

    float* zjb = (float*)d_ws;                  // [B*N, H] (512 KB)

    proj_kernel<<<dim3((BB * NN) / 4), dim3(64, 4), 0, stream>>>(
        z_t, W_r, b_r, zjb);
    pairsum_kernel<<<dim3(NN / ITILE, BB), dim3(64, 8), 0, stream>>>(
        z_t, W_r, zjb, W_a, b_a, out);
}

// Round 8
// 79.868 us; speedup vs baseline: 1.0101x; 1.0101x over previous
//
#include <hip/hip_runtime.h>
#include <hip/hip_bf16.h>

// Problem: B=2, N=1024, D=30, H=64, O=30  (all fp32)
//   zi = z @ W_r[:D], zj = z @ W_r[D:]
//   r_sum[b,i,h] = sum_j relu(zi[b,i,h] + zj[b,j,h] + b_r[h])
//   out[b,i,o]   = relu(sum_h r_sum[b,i,h]*W_a[h,o] + b_a[o])
//
// FINAL (R8 = exact R4 revert, the measured best at 79.6 us):
//   - dur_us budget: ~74-75 us harness fixed cost (one 268 MB d_ws poison
//     fill @ 83% HBM peak = 40.3 us + ~34 us restore/replay gaps) +
//     ~5 us kernel portion (2 us L2-bound staging + 3 us VALU issue).
//   - Tried and rejected: packed-f32/register-prefetch (R2, +10 us),
//     cooperative fused launch (R5, breaks graph capture), relu->abs
//     identity (R6, +0.6), zi-fold into pairsum (R7, +1.1).
//   - pairsum: 512-thread blocks, 8 waves = 2 waves/SIMD (the R4 win:
//     -6 us vs 1 wave/SIMD — LDS latency hiding), j-range split in half
//     across wave quads, 3 VALU/row/j inner loop (algorithmic minimum),
//     fused H->O epilogue from LDS.

#define BB 2
#define NN 1024
#define DD 30
#define HH 64
#define OO 30
#define JT 128      // j-tile rows staged in LDS per half (32 KB)
#define ITILE 8     // i rows per block

typedef float v2f __attribute__((ext_vector_type(2)));

// Kernel A: compute zi[b,n,h] and zjb[b,n,h] = zj + b_r  (b_r folded here)
__global__ __launch_bounds__(256) void proj_kernel(
    const float* __restrict__ z,    // [B*N, D]
    const float* __restrict__ Wr,   // [2D, H]
    const float* __restrict__ br,   // [H]
    float* __restrict__ zi_out,     // [B*N, H]
    float* __restrict__ zjb_out)    // [B*N, H]
{
    const int h = threadIdx.x;                      // 0..63
    const int r = blockIdx.x * 4 + threadIdx.y;     // row in [0, B*N)
    const float* zrow = z + (size_t)r * DD;
    float wi = 0.f, wj = 0.f;
#pragma unroll
    for (int d = 0; d < DD; ++d) {
        const float zv = zrow[d];                   // wave-uniform (scalar)
        wi += zv * Wr[d * HH + h];                  // coalesced across lanes
        wj += zv * Wr[(DD + d) * HH + h];
    }
    zi_out [(size_t)r * HH + h] = wi;
    zjb_out[(size_t)r * HH + h] = wj + br[h];
}

// Kernel B: pairwise relu-sum over j, fused with the H->O epilogue GEMM.
// Grid: (N/ITILE, B). Block: (64, 8) = 512 threads, 8 waves.
// Waves 0-3 (half 0) process j in [0,512); waves 4-7 (half 1) j in [512,1024).
// Within a half, wave q owns i-rows i0+2q, i0+2q+1. 2 waves/SIMD hide LDS
// latency. Halves' partial sums combine in LDS before the epilogue.
__global__ __launch_bounds__(512) void pairsum_kernel(
    const float* __restrict__ zi,    // [B*N, H]
    const float* __restrict__ zjb,   // [B*N, H]
    const float* __restrict__ Wa,    // [H, O]
    const float* __restrict__ ba,    // [O]
    float* __restrict__ out)         // [B*N, O]
{
    __shared__ float sj[2][JT * HH];        // 2 x 32 KB j-tiles
    __shared__ float racc[2][ITILE][HH];    // 2 x 2 KB partial r_sum rows

    const int h  = threadIdx.x;          // 0..63
    const int w  = threadIdx.y;          // 0..7
    const int hf = w >> 2;               // j-half: 0 or 1
    const int wq = w & 3;                // wave-quad index within half
    const int t4 = wq * 64 + h;          // 0..255 within half
    const int b  = blockIdx.y;
    const int i0 = blockIdx.x * ITILE;

    const float* zbase = zi + ((size_t)b * NN + i0) * HH;
    v2f zv;
    zv.x = zbase[(wq * 2 + 0) * HH + h];
    zv.y = zbase[(wq * 2 + 1) * HH + h];
    v2f acc = {0.f, 0.f};

    // this half's 512-row slab of zjb
    const float* slab = zjb + ((size_t)b * NN + hf * (NN / 2)) * HH;

    for (int tile = 0; tile < (NN / 2) / JT; ++tile) {
        // cooperative stage: JT*HH = 8192 floats = 2048 float4, 8/thread
        const float4* src = (const float4*)(slab + (size_t)tile * JT * HH);
        float4* dst = (float4*)sj[hf];
#pragma unroll
        for (int k = 0; k < 8; ++k) dst[t4 + k * 256] = src[t4 + k * 256];
        __syncthreads();
        const float* sjt = sj[hf];
#pragma unroll 8
        for (int j = 0; j < JT; ++j) {
            const float zjv = sjt[j * HH + h];   // 2-way bank alias: free
            v2f tt = zv + zjv;                   // packable: v_pk_add_f32
            tt.x = fmaxf(tt.x, 0.f);             // v_max_f32 on pair regs
            tt.y = fmaxf(tt.y, 0.f);
            acc += tt;                           // packable: v_pk_add_f32
        }
        __syncthreads();
    }

    racc[hf][wq * 2 + 0][h] = acc.x;
    racc[hf][wq * 2 + 1][h] = acc.y;
    __syncthreads();

    // Epilogue: 8 rows x 30 outputs = 240 dots of length 64 (threads t<256)
    const int t = w * 64 + h;
    const int i = t >> 5;        // 0..7 for t<256
    const int o = t & 31;        // 0..31
    if (t < 256 && o < OO) {
        float s = ba[o];
#pragma unroll
        for (int hh = 0; hh < HH; ++hh)
            s += (racc[0][i][hh] + racc[1][i][hh]) * Wa[hh * OO + o];
        out[((size_t)b * NN + i0 + i) * OO + o] = fmaxf(s, 0.f);
    }
}

extern "C" void kernel_launch(void* const* d_in, const int* in_sizes, int n_in,
                              void* d_out, int out_size, void* d_ws, size_t ws_size,
                              hipStream_t stream) {
    const float* z_t = (const float*)d_in[0];   // [B,N,D]
    const float* W_r = (const float*)d_in[1];   // [2D,H]
    const float* b_r = (const float*)d_in[2];   // [H]
    const float* W_a = (const float*)d_in[3];   // [H,O]
    const float* b_a = (const float*)d_in[4];   // [O]
    float* out = (float*)d_out;                 // [B,N,O]

    float* zi  = (float*)d_ws;                  // B*N*H floats
    float* zjb = zi + (size_t)BB * NN * HH;     // B*N*H floats (1 MB total)

    proj_kernel<<<dim3((BB * NN) / 4), dim3(64, 4), 0, stream>>>(
        z_t, W_r, b_r, zi, zjb);
    pairsum_kernel<<<dim3(NN / ITILE, BB), dim3(64, 8), 0, stream>>>(
        zi, zjb, W_a, b_a, out);
}